// Round 1
// baseline (2926.511 us; speedup 1.0000x reference)
//
#include <hip/hip_runtime.h>
#include <hip/hip_bf16.h>
#include <math.h>

#define DF 128           // feature dim (both in and out)
#define TILE_EDGES 6144  // edges per bin tile (P1/P3) -> 521 blocks
#define NPB 64           // nodes per bucket (bucket = col >> 6)
#define BSH 6            // bucket shift
#define NB_MAX 2048      // max buckets (supports N <= 131072)
#define KP 136           // padded K stride (bf16) for W^T LDS tile
#define BPG 2            // buckets per gather block

typedef __hip_bfloat16 bf16;
typedef __hip_bfloat162 bf16x2;
typedef __attribute__((ext_vector_type(8))) short short8;
typedef __attribute__((ext_vector_type(4))) float f32x4;

__device__ inline short bf16bits(float f) {
    __hip_bfloat16 h = __float2bfloat16(f);
    return *reinterpret_cast<short*>(&h);
}

// ---------------- P1: per-tile LDS histogram over buckets ----------------
// counts laid out bucket-major: counts[b*T + t]
__global__ __launch_bounds__(512) void k_binc(const int* __restrict__ col,
                                              int* __restrict__ counts,
                                              int E, int T, int NB) {
    __shared__ int h[NB_MAX];
    int tid = threadIdx.x;
    for (int i = tid; i < NB; i += 512) h[i] = 0;
    __syncthreads();
    int tileBase = blockIdx.x * TILE_EDGES;
    for (int j = 0; j < TILE_EDGES / 512; ++j) {
        int e = tileBase + j * 512 + tid;
        if (e < E) atomicAdd(&h[col[e] >> BSH], 1);
    }
    __syncthreads();
    for (int b = tid; b < NB; b += 512)
        counts[b * T + blockIdx.x] = h[b];
}

// ---------------- scan of counts (M = NB*T elements), 3-phase ----------------
__global__ __launch_bounds__(256) void k_scanA(int* __restrict__ data,
                                               int* __restrict__ blockSums, int M) {
    __shared__ int tmp[256];
    int tid = threadIdx.x;
    int n = blockIdx.x * 256 + tid;
    int v = (n < M) ? data[n] : 0;
    tmp[tid] = v;
    __syncthreads();
    for (int off = 1; off < 256; off <<= 1) {
        int t = (tid >= off) ? tmp[tid - off] : 0;
        __syncthreads();
        tmp[tid] += t;
        __syncthreads();
    }
    if (tid == 255) blockSums[blockIdx.x] = tmp[255];
    if (n < M) data[n] = tmp[tid] - v;  // exclusive within block (in-place)
}

// loop-carry scan of nb block sums (nb can exceed 1024)
__global__ __launch_bounds__(1024) void k_scanB(int* __restrict__ blockSums, int nb) {
    __shared__ int tmp[1024];
    int tid = threadIdx.x;
    int carry = 0;
    for (int c0 = 0; c0 < nb; c0 += 1024) {
        int n = c0 + tid;
        int v = (n < nb) ? blockSums[n] : 0;
        tmp[tid] = v;
        __syncthreads();
        for (int off = 1; off < 1024; off <<= 1) {
            int t = (tid >= off) ? tmp[tid - off] : 0;
            __syncthreads();
            tmp[tid] += t;
            __syncthreads();
        }
        if (n < nb) blockSums[n] = carry + tmp[tid] - v;  // exclusive
        int total = tmp[1023];  // safe: last op above was a sync'd read pattern
        carry += total;
        __syncthreads();  // protect tmp before next chunk overwrites
    }
}

__global__ __launch_bounds__(256) void k_scanC(int* __restrict__ data,
                                               const int* __restrict__ blockSums,
                                               int* __restrict__ bucketBase,
                                               int M, int T, int NB, int E) {
    int n = blockIdx.x * 256 + threadIdx.x;
    if (n >= M) return;
    int v = data[n] + blockSums[n >> 8];
    data[n] = v;                                   // global tile offsets
    if (n % T == 0) bucketBase[n / T] = v;         // bucket start = offset of its tile 0
    if (n == 0) bucketBase[NB] = E;
}

// ---------------- P3: scatter edges into buckets (LDS cursors, no global atomics) ----
// binned[pos] = (localNode << 24) | row   (row < 2^24, localNode < 64)
__global__ __launch_bounds__(512) void k_binscatter(const int* __restrict__ edge,
                                                    const int* __restrict__ tileOff,
                                                    unsigned* __restrict__ binned,
                                                    int E, int T, int NB) {
    __shared__ int cur[NB_MAX];
    int tid = threadIdx.x;
    int t = blockIdx.x;
    for (int b = tid; b < NB; b += 512) cur[b] = tileOff[b * T + t];
    __syncthreads();
    int tileBase = t * TILE_EDGES;
    for (int j = 0; j < TILE_EDGES / 512; ++j) {
        int e = tileBase + j * 512 + tid;
        if (e < E) {
            int r = edge[e];
            int c = edge[E + e];
            int pos = atomicAdd(&cur[c >> BSH], 1);
            binned[pos] = ((unsigned)(c & (NPB - 1)) << 24) | (unsigned)r;
        }
    }
}

// ---------------- P4: per-bucket degree histogram -> dinv (needed by GEMM) --------
__global__ __launch_bounds__(256) void k_deg(const unsigned* __restrict__ binned,
                                             const int* __restrict__ bucketBase,
                                             float* __restrict__ dinv, int N) {
    __shared__ int h[NPB];
    int tid = threadIdx.x;
    int b = blockIdx.x;
    if (tid < NPB) h[tid] = 0;
    __syncthreads();
    int base = bucketBase[b];
    int cnt = bucketBase[b + 1] - base;
    for (int i = tid; i < cnt; i += 256)
        atomicAdd(&h[binned[base + i] >> 24], 1);
    __syncthreads();
    int node = b * NPB + tid;
    if (tid < NPB && node < N)
        dinv[node] = rsqrtf((float)(h[tid] + 1));  // +1 self-loop
}

// ---------------- MFMA GEMM: y = bf16((x @ W) * dinv[row]) ----------------
// 16x16x32 bf16 MFMA. A-frag: A[m=lane&15][k=quad*8+j]; B-frag: B[k=quad*8+j][n=lane&15];
// C/D: col=lane&15, row=quad*4+reg (m89-verified layouts).
// W staged transposed (Wt[n][k], stride KP=136) in LDS -> ds_read_b128 per b-frag.
__global__ __launch_bounds__(256) void k_gemm(const float* __restrict__ x,
                                              const float* __restrict__ W,
                                              const float* __restrict__ dinv,
                                              bf16* __restrict__ y, int N) {
    __shared__ bf16 Wt[DF * KP];  // 34 KB
    int tid = threadIdx.x;
    // stage W -> Wt (transpose + f32->bf16)
    for (int i = tid; i < DF * (DF / 4); i += 256) {
        int k = i >> 5;           // 0..127
        int n4 = (i & 31) * 4;    // 0..124 step 4
        float4 w = *(const float4*)(W + k * DF + n4);
        Wt[(n4 + 0) * KP + k] = __float2bfloat16(w.x);
        Wt[(n4 + 1) * KP + k] = __float2bfloat16(w.y);
        Wt[(n4 + 2) * KP + k] = __float2bfloat16(w.z);
        Wt[(n4 + 3) * KP + k] = __float2bfloat16(w.w);
    }
    __syncthreads();

    const int wv = tid >> 6;       // wave 0..3
    const int lane = tid & 63;
    const int m16 = lane & 15;
    const int q = lane >> 4;       // quad 0..3
    const int rbase = blockIdx.x * 64 + wv * 16;
    const int arow = min(rbase + m16, N - 1);   // clamped A row for tail block

    f32x4 acc[8];
#pragma unroll
    for (int nt = 0; nt < 8; ++nt) acc[nt] = (f32x4){0.f, 0.f, 0.f, 0.f};

#pragma unroll
    for (int kc = 0; kc < 4; ++kc) {
        int k0 = kc * 32 + q * 8;
        float4 xa = *(const float4*)(x + (size_t)arow * DF + k0);
        float4 xb = *(const float4*)(x + (size_t)arow * DF + k0 + 4);
        short8 a;
        a[0] = bf16bits(xa.x); a[1] = bf16bits(xa.y);
        a[2] = bf16bits(xa.z); a[3] = bf16bits(xa.w);
        a[4] = bf16bits(xb.x); a[5] = bf16bits(xb.y);
        a[6] = bf16bits(xb.z); a[7] = bf16bits(xb.w);
#pragma unroll
        for (int nt = 0; nt < 8; ++nt) {
            short8 b = *(const short8*)(Wt + (nt * 16 + m16) * KP + k0);
            acc[nt] = __builtin_amdgcn_mfma_f32_16x16x32_bf16(a, b, acc[nt], 0, 0, 0);
        }
    }

    // epilogue: scale by dinv[row], store bf16
#pragma unroll
    for (int r = 0; r < 4; ++r) {
        int orow = rbase + q * 4 + r;
        if (orow < N) {
            float dv = dinv[orow];
#pragma unroll
            for (int nt = 0; nt < 8; ++nt) {
                y[(size_t)orow * DF + nt * 16 + m16] = __float2bfloat16(acc[nt][r] * dv);
            }
        }
    }
}

// ---------------- gather-aggregate: per-bucket f32 accumulators in LDS ----------
// Block handles BPG buckets sequentially. acc split into two [NPB][64] planes so
// ds_add_f32 addresses are stride-1 (2-way bank alias = free). No per-node sort,
// no ssrc: consumes 'binned' (bucket-grouped) directly; ds_add is return-free so
// there is no serial accumulate chain -> loads pipeline freely.
__global__ __launch_bounds__(512) void k_gather(const bf16x2* __restrict__ y,  // stride 64/row
                                                const unsigned* __restrict__ binned,
                                                const int* __restrict__ bucketBase,
                                                const float* __restrict__ dinv,
                                                const float* __restrict__ bvec,
                                                float* __restrict__ out, int N, int NB) {
    __shared__ float acc0[NPB][64];  // feature 2*lane
    __shared__ float acc1[NPB][64];  // feature 2*lane+1
    int tid = threadIdx.x;
    int lane = tid & 63;
    int wv = tid >> 6;  // 8 waves

    for (int pass = 0; pass < BPG; ++pass) {
        int b = blockIdx.x * BPG + pass;
        if (b >= NB) break;
        if (pass) __syncthreads();
        int base = bucketBase[b];
        int cnt = bucketBase[b + 1] - base;
        int nodeBase = b * NPB;

        // init: self-loop term y[c] (rows beyond N -> zero, never read back)
        for (int t = wv; t < NPB; t += 8) {
            int c = nodeBase + t;
            float2 v = make_float2(0.f, 0.f);
            if (c < N) v = __bfloat1622float2(y[(size_t)c * 64 + lane]);
            acc0[t][lane] = v.x;
            acc1[t][lane] = v.y;
        }
        __syncthreads();

        // edge loop: each wave takes 64-edge chunks
        for (int i0 = wv * 64; i0 < cnt; i0 += 512) {
            int nb = min(64, cnt - i0);
            unsigned ev = binned[base + i0 + min(lane, nb - 1)];  // coalesced, clamped
            int j = 0;
            for (; j + 8 <= nb; j += 8) {
                unsigned u0 = (unsigned)__shfl((int)ev, j + 0);
                unsigned u1 = (unsigned)__shfl((int)ev, j + 1);
                unsigned u2 = (unsigned)__shfl((int)ev, j + 2);
                unsigned u3 = (unsigned)__shfl((int)ev, j + 3);
                unsigned u4 = (unsigned)__shfl((int)ev, j + 4);
                unsigned u5 = (unsigned)__shfl((int)ev, j + 5);
                unsigned u6 = (unsigned)__shfl((int)ev, j + 6);
                unsigned u7 = (unsigned)__shfl((int)ev, j + 7);
                float2 v0 = __bfloat1622float2(y[(size_t)(u0 & 0xFFFFFFu) * 64 + lane]);
                float2 v1 = __bfloat1622float2(y[(size_t)(u1 & 0xFFFFFFu) * 64 + lane]);
                float2 v2 = __bfloat1622float2(y[(size_t)(u2 & 0xFFFFFFu) * 64 + lane]);
                float2 v3 = __bfloat1622float2(y[(size_t)(u3 & 0xFFFFFFu) * 64 + lane]);
                float2 v4 = __bfloat1622float2(y[(size_t)(u4 & 0xFFFFFFu) * 64 + lane]);
                float2 v5 = __bfloat1622float2(y[(size_t)(u5 & 0xFFFFFFu) * 64 + lane]);
                float2 v6 = __bfloat1622float2(y[(size_t)(u6 & 0xFFFFFFu) * 64 + lane]);
                float2 v7 = __bfloat1622float2(y[(size_t)(u7 & 0xFFFFFFu) * 64 + lane]);
                atomicAdd(&acc0[u0 >> 24][lane], v0.x); atomicAdd(&acc1[u0 >> 24][lane], v0.y);
                atomicAdd(&acc0[u1 >> 24][lane], v1.x); atomicAdd(&acc1[u1 >> 24][lane], v1.y);
                atomicAdd(&acc0[u2 >> 24][lane], v2.x); atomicAdd(&acc1[u2 >> 24][lane], v2.y);
                atomicAdd(&acc0[u3 >> 24][lane], v3.x); atomicAdd(&acc1[u3 >> 24][lane], v3.y);
                atomicAdd(&acc0[u4 >> 24][lane], v4.x); atomicAdd(&acc1[u4 >> 24][lane], v4.y);
                atomicAdd(&acc0[u5 >> 24][lane], v5.x); atomicAdd(&acc1[u5 >> 24][lane], v5.y);
                atomicAdd(&acc0[u6 >> 24][lane], v6.x); atomicAdd(&acc1[u6 >> 24][lane], v6.y);
                atomicAdd(&acc0[u7 >> 24][lane], v7.x); atomicAdd(&acc1[u7 >> 24][lane], v7.y);
            }
            for (; j < nb; ++j) {
                unsigned u = (unsigned)__shfl((int)ev, j);
                float2 v = __bfloat1622float2(y[(size_t)(u & 0xFFFFFFu) * 64 + lane]);
                atomicAdd(&acc0[u >> 24][lane], v.x);
                atomicAdd(&acc1[u >> 24][lane], v.y);
            }
        }
        __syncthreads();

        // epilogue: out = relu(acc * dinv[c] + b)
        for (int t = wv; t < NPB; t += 8) {
            int c = nodeBase + t;
            if (c < N) {
                float dv = dinv[c];
                float2 bb = *(const float2*)(bvec + lane * 2);
                float2 o;
                o.x = fmaxf(fmaf(dv, acc0[t][lane], bb.x), 0.0f);
                o.y = fmaxf(fmaf(dv, acc1[t][lane], bb.y), 0.0f);
                *(float2*)(out + (size_t)c * DF + lane * 2) = o;
            }
        }
    }
}

extern "C" void kernel_launch(void* const* d_in, const int* in_sizes, int n_in,
                              void* d_out, int out_size, void* d_ws, size_t ws_size,
                              hipStream_t stream) {
    const float* x    = (const float*)d_in[0];
    const int*   edge = (const int*)d_in[1];   // [2, E] flat: rows then cols
    const float* W    = (const float*)d_in[2];
    const float* b    = (const float*)d_in[3];
    float*       out  = (float*)d_out;

    const int N = in_sizes[0] / DF;   // 100000
    const int E = in_sizes[1] / 2;    // 3200000

    const int T  = (E + TILE_EDGES - 1) / TILE_EDGES;   // 521 bin tiles
    const int NB = (N + NPB - 1) / NPB;                 // 1563 buckets (<= NB_MAX)
    const int M  = NB * T;                              // ~814K counts

    // workspace layout (base is 16B-aligned)
    bf16*     y          = (bf16*)d_ws;              // N*128 bf16 (25.6 MB)
    float*    dinv       = (float*)(y + (size_t)N * DF);
    int*      bucketBase = (int*)(dinv + N);         // NB+1 (pad to NB_MAX+8)
    int*      blockSums  = bucketBase + NB_MAX + 8;  // 4096 slots
    int*      counts     = blockSums + 4096;         // M ints (~3.3 MB)
    unsigned* binned     = (unsigned*)(counts + M);  // E uints (12.8 MB)

    const int nbM = (M + 255) / 256;                 // ~3181 (<=4096 blockSums)

    k_binc<<<T, 512, 0, stream>>>(edge + E, counts, E, T, NB);
    k_scanA<<<nbM, 256, 0, stream>>>(counts, blockSums, M);
    k_scanB<<<1, 1024, 0, stream>>>(blockSums, nbM);
    k_scanC<<<nbM, 256, 0, stream>>>(counts, blockSums, bucketBase, M, T, NB, E);
    k_binscatter<<<T, 512, 0, stream>>>(edge, counts, binned, E, T, NB);
    k_deg<<<NB, 256, 0, stream>>>(binned, bucketBase, dinv, N);
    k_gemm<<<(N + 63) / 64, 256, 0, stream>>>(x, W, dinv, y, N);
    k_gather<<<(NB + BPG - 1) / BPG, 512, 0, stream>>>((const bf16x2*)y, binned, bucketBase,
                                                       dinv, b, out, N, NB);
}

// Round 3
// 337.245 us; speedup vs baseline: 8.6777x; 8.6777x over previous
//
#include <hip/hip_runtime.h>
#include <hip/hip_bf16.h>
#include <math.h>

#define DF 128           // feature dim (both in and out)
#define TILE_EDGES 6144  // edges per scatter tile -> 521 blocks
#define NPB 256          // nodes per bucket (bucket = col >> 8)
#define NB_MAX 512       // max buckets (supports N <= 131072)
#define KP 136           // padded K stride (bf16) for W^T LDS tile

typedef __hip_bfloat16 bf16;
typedef __hip_bfloat162 bf16x2;
typedef __attribute__((ext_vector_type(8))) short short8;
typedef __attribute__((ext_vector_type(4))) float f32x4;

__device__ inline short bf16bits(float f) {
    __hip_bfloat16 h = __float2bfloat16(f);
    return *reinterpret_cast<short*>(&h);
}

// unpack two packed bf16x2 dwords (carried in a float2) to 4 f32 features
__device__ inline float4 unpack4(float2 p) {
    unsigned u0 = __float_as_uint(p.x), u1 = __float_as_uint(p.y);
    float4 r;
    r.x = __uint_as_float(u0 << 16);
    r.y = __uint_as_float(u0 & 0xffff0000u);
    r.z = __uint_as_float(u1 << 16);
    r.w = __uint_as_float(u1 & 0xffff0000u);
    return r;
}

// ---------------- P1: bucket histogram (LDS per block, one global atomic merge) ----
__global__ __launch_bounds__(512) void k_hist(const int* __restrict__ col,
                                              int* __restrict__ bucketCnt,
                                              int E, int NB) {
    __shared__ int h[NB_MAX];
    int tid = threadIdx.x;
    for (int i = tid; i < NB; i += 512) h[i] = 0;
    __syncthreads();
    for (int e = blockIdx.x * 512 + tid; e < E; e += gridDim.x * 512)
        atomicAdd(&h[col[e] >> 8], 1);
    __syncthreads();
    for (int i = tid; i < NB; i += 512)
        if (h[i]) atomicAdd(&bucketCnt[i], h[i]);
}

// ---------------- P2: tiny scan over NB buckets (one block) ----------------
__global__ __launch_bounds__(512) void k_scanbkt(const int* __restrict__ bucketCnt,
                                                 int* __restrict__ bucketBase,
                                                 int* __restrict__ cursor,
                                                 int NB, int E) {
    __shared__ int tmp[512];
    int tid = threadIdx.x;
    int v = (tid < NB) ? bucketCnt[tid] : 0;
    tmp[tid] = v;
    __syncthreads();
    for (int off = 1; off < 512; off <<= 1) {
        int t = (tid >= off) ? tmp[tid - off] : 0;
        __syncthreads();
        tmp[tid] += t;
        __syncthreads();
    }
    if (tid < NB) {
        int excl = tmp[tid] - v;
        bucketBase[tid] = excl;
        cursor[tid] = excl;
    }
    if (tid == 0) bucketBase[NB] = E;
}

// ---------------- P3: scatter edges into buckets (atomic space reservation) -------
// binned[pos] = (localNode << 24) | row   (row < 2^24, localNode < 256)
__global__ __launch_bounds__(512) void k_binscatter(const int* __restrict__ edge,
                                                    int* __restrict__ cursor,
                                                    unsigned* __restrict__ binned,
                                                    int E, int NB) {
    __shared__ int h[NB_MAX];
    __shared__ int curl[NB_MAX];
    int tid = threadIdx.x;
    int tileBase = blockIdx.x * TILE_EDGES;
    for (int i = tid; i < NB; i += 512) h[i] = 0;
    __syncthreads();
    // pass 1: count this tile's bucket occupancy
    for (int j = 0; j < TILE_EDGES / 512; ++j) {
        int e = tileBase + j * 512 + tid;
        if (e < E) atomicAdd(&h[edge[E + e] >> 8], 1);
    }
    __syncthreads();
    // reserve contiguous space per bucket
    for (int i = tid; i < NB; i += 512)
        curl[i] = h[i] ? atomicAdd(&cursor[i], h[i]) : 0;
    __syncthreads();
    // pass 2: scatter (tile is L1/L2-hot from pass 1)
    for (int j = 0; j < TILE_EDGES / 512; ++j) {
        int e = tileBase + j * 512 + tid;
        if (e < E) {
            int r = edge[e];
            int c = edge[E + e];
            int pos = atomicAdd(&curl[c >> 8], 1);
            binned[pos] = ((unsigned)(c & (NPB - 1)) << 24) | (unsigned)r;
        }
    }
}

// ---------------- P4: per-bucket counting sort in LDS; emits CSR + deg + dinv -------
__global__ __launch_bounds__(512) void k_bucket(const unsigned* __restrict__ binned,
                                                const int* __restrict__ bucketBase,
                                                int* __restrict__ ssrc,
                                                int* __restrict__ offsets,
                                                int* __restrict__ deg,
                                                float* __restrict__ dinv, int N) {
    __shared__ int h[NPB], sc[NPB], cur[NPB];
    int tid = threadIdx.x;
    int b = blockIdx.x;
    int base = bucketBase[b];
    int cnt = bucketBase[b + 1] - base;
    if (tid < NPB) h[tid] = 0;
    __syncthreads();
    for (int i = tid; i < cnt; i += 512)
        atomicAdd(&h[binned[base + i] >> 24], 1);
    __syncthreads();
    // exclusive scan of h (256 entries)
    if (tid < NPB) sc[tid] = h[tid];
    __syncthreads();
    for (int off = 1; off < NPB; off <<= 1) {
        int tv = (tid >= off && tid < NPB) ? sc[tid - off] : 0;
        __syncthreads();
        if (tid < NPB) sc[tid] += tv;
        __syncthreads();
    }
    if (tid < NPB) {
        int excl = sc[tid] - h[tid];
        cur[tid] = base + excl;
        int node = b * NPB + tid;
        if (node < N) {
            offsets[node] = base + excl;
            deg[node] = h[tid];
            dinv[node] = rsqrtf((float)(h[tid] + 1));  // +1 self-loop
        }
    }
    __syncthreads();
    for (int i = tid; i < cnt; i += 512) {
        unsigned v = binned[base + i];
        int pos = atomicAdd(&cur[v >> 24], 1);
        ssrc[pos] = (int)(v & 0xFFFFFFu);
    }
}

// ---------------- MFMA GEMM: y = bf16((x @ W) * dinv[row]) ----------------
// 16x16x32 bf16 MFMA. A-frag: A[m=lane&15][k=quad*8+j]; B-frag: B[k=quad*8+j][n=lane&15];
// C/D: col=lane&15, row=quad*4+reg (m89-verified layouts).
// W staged transposed (Wt[n][k], stride KP=136) in LDS -> ds_read_b128 per b-frag.
__global__ __launch_bounds__(256) void k_gemm(const float* __restrict__ x,
                                              const float* __restrict__ W,
                                              const float* __restrict__ dinv,
                                              bf16* __restrict__ y, int N) {
    __shared__ bf16 Wt[DF * KP];  // 34 KB
    int tid = threadIdx.x;
    // stage W -> Wt (transpose + f32->bf16)
    for (int i = tid; i < DF * (DF / 4); i += 256) {
        int k = i >> 5;           // 0..127
        int n4 = (i & 31) * 4;    // 0..124 step 4
        float4 w = *(const float4*)(W + k * DF + n4);
        Wt[(n4 + 0) * KP + k] = __float2bfloat16(w.x);
        Wt[(n4 + 1) * KP + k] = __float2bfloat16(w.y);
        Wt[(n4 + 2) * KP + k] = __float2bfloat16(w.z);
        Wt[(n4 + 3) * KP + k] = __float2bfloat16(w.w);
    }
    __syncthreads();

    const int wv = tid >> 6;       // wave 0..3
    const int lane = tid & 63;
    const int m16 = lane & 15;
    const int q = lane >> 4;       // quad 0..3
    const int rbase = blockIdx.x * 64 + wv * 16;
    const int arow = min(rbase + m16, N - 1);   // clamped A row for tail block

    f32x4 acc[8];
#pragma unroll
    for (int nt = 0; nt < 8; ++nt) acc[nt] = (f32x4){0.f, 0.f, 0.f, 0.f};

#pragma unroll
    for (int kc = 0; kc < 4; ++kc) {
        int k0 = kc * 32 + q * 8;
        float4 xa = *(const float4*)(x + (size_t)arow * DF + k0);
        float4 xb = *(const float4*)(x + (size_t)arow * DF + k0 + 4);
        short8 a;
        a[0] = bf16bits(xa.x); a[1] = bf16bits(xa.y);
        a[2] = bf16bits(xa.z); a[3] = bf16bits(xa.w);
        a[4] = bf16bits(xb.x); a[5] = bf16bits(xb.y);
        a[6] = bf16bits(xb.z); a[7] = bf16bits(xb.w);
#pragma unroll
        for (int nt = 0; nt < 8; ++nt) {
            short8 b = *(const short8*)(Wt + (nt * 16 + m16) * KP + k0);
            acc[nt] = __builtin_amdgcn_mfma_f32_16x16x32_bf16(a, b, acc[nt], 0, 0, 0);
        }
    }

    // epilogue: scale by dinv[row], store bf16
#pragma unroll
    for (int r = 0; r < 4; ++r) {
        int orow = rbase + q * 4 + r;
        if (orow < N) {
            float dv = dinv[orow];
#pragma unroll
            for (int nt = 0; nt < 8; ++nt) {
                y[(size_t)orow * DF + nt * 16 + m16] = __float2bfloat16(acc[nt][r] * dv);
            }
        }
    }
}

// ---------------- gather-aggregate: one wave per target node, paired-edge loads ----
// Half-wave per neighbor row: 32 lanes x float2 (8B) covers one 256B y-row; each
// load instruction fetches TWO rows -> half the VMEM instructions, 16 edges in
// flight per unrolled block. bf16 unpack via shift/mask (exact).
__global__ __launch_bounds__(256) void k_gather(const float* __restrict__ yf,  // y as dwords, stride 64/row
                                                const int* __restrict__ ssrc,
                                                const int* __restrict__ offsets,
                                                const int* __restrict__ deg,
                                                const float* __restrict__ dinv,
                                                const float* __restrict__ bvec,
                                                float* __restrict__ out, int N) {
    int wave = (blockIdx.x * 256 + threadIdx.x) >> 6;  // 4 waves/block = 4 nodes
    int lane = threadIdx.x & 63;
    if (wave >= N) return;
    int c = wave;
    int start = offsets[c];
    int d = deg[c];
    int half = lane >> 5;   // 0/1: which edge of a pair this half-wave handles
    int l32 = lane & 31;    // covers features 4*l32 .. 4*l32+3

    // self-loop term on half 0; half 1 starts at zero
    float4 acc = make_float4(0.f, 0.f, 0.f, 0.f);
    if (half == 0) {
        float2 sv = *(const float2*)(yf + (size_t)c * 64 + l32 * 2);
        acc = unpack4(sv);
    }

    for (int base = 0; base < d; base += 64) {
        int nb = min(64, d - base);                       // nb >= 1 here
        int idx = ssrc[start + base + min(lane, nb - 1)]; // coalesced, clamped
        int j = 0;
        for (; j + 16 <= nb; j += 16) {
            int ra0 = __shfl(idx, j + 0),  rb0 = __shfl(idx, j + 1);
            int ra1 = __shfl(idx, j + 2),  rb1 = __shfl(idx, j + 3);
            int ra2 = __shfl(idx, j + 4),  rb2 = __shfl(idx, j + 5);
            int ra3 = __shfl(idx, j + 6),  rb3 = __shfl(idx, j + 7);
            int ra4 = __shfl(idx, j + 8),  rb4 = __shfl(idx, j + 9);
            int ra5 = __shfl(idx, j + 10), rb5 = __shfl(idx, j + 11);
            int ra6 = __shfl(idx, j + 12), rb6 = __shfl(idx, j + 13);
            int ra7 = __shfl(idx, j + 14), rb7 = __shfl(idx, j + 15);
            int r0 = half ? rb0 : ra0;
            int r1 = half ? rb1 : ra1;
            int r2 = half ? rb2 : ra2;
            int r3 = half ? rb3 : ra3;
            int r4 = half ? rb4 : ra4;
            int r5 = half ? rb5 : ra5;
            int r6 = half ? rb6 : ra6;
            int r7 = half ? rb7 : ra7;
            float2 v0 = *(const float2*)(yf + (size_t)r0 * 64 + l32 * 2);
            float2 v1 = *(const float2*)(yf + (size_t)r1 * 64 + l32 * 2);
            float2 v2 = *(const float2*)(yf + (size_t)r2 * 64 + l32 * 2);
            float2 v3 = *(const float2*)(yf + (size_t)r3 * 64 + l32 * 2);
            float2 v4 = *(const float2*)(yf + (size_t)r4 * 64 + l32 * 2);
            float2 v5 = *(const float2*)(yf + (size_t)r5 * 64 + l32 * 2);
            float2 v6 = *(const float2*)(yf + (size_t)r6 * 64 + l32 * 2);
            float2 v7 = *(const float2*)(yf + (size_t)r7 * 64 + l32 * 2);
            float4 u0 = unpack4(v0), u1 = unpack4(v1), u2 = unpack4(v2), u3 = unpack4(v3);
            float4 u4 = unpack4(v4), u5 = unpack4(v5), u6 = unpack4(v6), u7 = unpack4(v7);
            acc.x += ((u0.x + u1.x) + (u2.x + u3.x)) + ((u4.x + u5.x) + (u6.x + u7.x));
            acc.y += ((u0.y + u1.y) + (u2.y + u3.y)) + ((u4.y + u5.y) + (u6.y + u7.y));
            acc.z += ((u0.z + u1.z) + (u2.z + u3.z)) + ((u4.z + u5.z) + (u6.z + u7.z));
            acc.w += ((u0.w + u1.w) + (u2.w + u3.w)) + ((u4.w + u5.w) + (u6.w + u7.w));
        }
        for (; j + 2 <= nb; j += 2) {
            int ra = __shfl(idx, j), rb = __shfl(idx, j + 1);
            int r = half ? rb : ra;
            float2 v = *(const float2*)(yf + (size_t)r * 64 + l32 * 2);
            float4 u = unpack4(v);
            acc.x += u.x; acc.y += u.y; acc.z += u.z; acc.w += u.w;
        }
        if (j < nb) {  // one leftover edge: half 0 only
            int r = __shfl(idx, j);
            if (half == 0) {
                float2 v = *(const float2*)(yf + (size_t)r * 64 + l32 * 2);
                float4 u = unpack4(v);
                acc.x += u.x; acc.y += u.y; acc.z += u.z; acc.w += u.w;
            }
        }
    }

    // combine the two half-wave partial sums
    acc.x += __shfl_xor(acc.x, 32);
    acc.y += __shfl_xor(acc.y, 32);
    acc.z += __shfl_xor(acc.z, 32);
    acc.w += __shfl_xor(acc.w, 32);

    if (half == 0) {
        float dv = dinv[c];
        float4 bb = *(const float4*)(bvec + l32 * 4);
        float4 o;
        o.x = fmaxf(fmaf(dv, acc.x, bb.x), 0.0f);
        o.y = fmaxf(fmaf(dv, acc.y, bb.y), 0.0f);
        o.z = fmaxf(fmaf(dv, acc.z, bb.z), 0.0f);
        o.w = fmaxf(fmaf(dv, acc.w, bb.w), 0.0f);
        *(float4*)(out + (size_t)c * DF + l32 * 4) = o;
    }
}

extern "C" void kernel_launch(void* const* d_in, const int* in_sizes, int n_in,
                              void* d_out, int out_size, void* d_ws, size_t ws_size,
                              hipStream_t stream) {
    const float* x    = (const float*)d_in[0];
    const int*   edge = (const int*)d_in[1];   // [2, E] flat: rows then cols
    const float* W    = (const float*)d_in[2];
    const float* b    = (const float*)d_in[3];
    float*       out  = (float*)d_out;

    const int N = in_sizes[0] / DF;   // 100000
    const int E = in_sizes[1] / 2;    // 3200000

    const int T  = (E + TILE_EDGES - 1) / TILE_EDGES;   // 521 scatter tiles
    const int NB = (N + NPB - 1) / NPB;                 // 391 buckets (<= NB_MAX)

    // workspace layout (base is 16B-aligned)
    bf16*     y          = (bf16*)d_ws;              // N*128 bf16 (25.6 MB)
    int*      deg        = (int*)(y + (size_t)N * DF);
    float*    dinv       = (float*)(deg + N);
    int*      offsets    = (int*)(dinv + N);
    int*      bucketBase = offsets + N;              // NB+1 (pad 8)
    int*      cursor     = bucketBase + NB_MAX + 8;  // NB
    int*      bucketCnt  = cursor + NB_MAX + 8;      // NB
    unsigned* binned     = (unsigned*)(bucketCnt + NB_MAX + 8);  // E uints (12.8 MB)
    int*      ssrc       = (int*)(binned + E);       // E ints (12.8 MB)

    (void)hipMemsetAsync(bucketCnt, 0, (NB + 1) * sizeof(int), stream);
    k_hist<<<512, 512, 0, stream>>>(edge + E, bucketCnt, E, NB);
    k_scanbkt<<<1, 512, 0, stream>>>(bucketCnt, bucketBase, cursor, NB, E);
    k_binscatter<<<T, 512, 0, stream>>>(edge, cursor, binned, E, NB);
    k_bucket<<<NB, 512, 0, stream>>>(binned, bucketBase, ssrc, offsets, deg, dinv, N);
    k_gemm<<<(N + 63) / 64, 256, 0, stream>>>(x, W, dinv, y, N);
    k_gather<<<(N + 3) / 4, 256, 0, stream>>>((const float*)y, ssrc, offsets, deg, dinv, b, out, N);
}